// Round 7
// baseline (70.803 us; speedup 1.0000x reference)
//
#include <hip/hip_runtime.h>
#include <hip/hip_bf16.h>
#include <float.h>
#include <math.h>

#define BB 64
#define T1 33
#define TT 32
#define II 197
#define CC 512
#define TEMP 0.07f

typedef float f32x4 __attribute__((ext_vector_type(4)));
typedef int i32x4 __attribute__((ext_vector_type(4)));
typedef int i32x8 __attribute__((ext_vector_type(8)));

// ---- workspace layout (bytes) ----
// Frag records for mfma_scale_f32_16x16x128_f8f6f4 (fp8): per frag per kstep,
// 2048 B = [half h 0..1][lane 0..63][16 B]; element (row/col = lane&15,
// k = ks*128 + (lane>>4)*32 + h*16 + j).
// tl8: [xc8 8][ks 4][fa 16] records  (1 MB)   A: text rows r=fa*16+(lane&15)
// ve8: [y 64][ks 4][fb 16] records  (8 MB)   B: cols  i=fb*16+(lane&15); fb<=12 written
// tti: [64 x][64 y] f32
#define TL_OFF  0
#define VE_OFF  (1 << 20)                  // 1 MB
#define TTI_OFF ((1 << 20) + (8 << 20))    // 9 MB
#define KS_STRIDE   32768                  // 16 frags * 2048
#define GRP_STRIDE  131072                 // 4 ks * KS_STRIDE

// grid (64, 8): hz 0..3 = video c-chunks (= ksteps), hz 4..7 = text c-chunks.
// 512 threads. Pass 1 caches the block's 100 KB row-chunk in LDS; pass 2
// builds fp8 records from LDS (inputs read from HBM exactly once, coalesced).
__global__ __launch_bounds__(512) void norm_all_kernel(const float* __restrict__ text,
                                                       const float* __restrict__ video,
                                                       unsigned char* __restrict__ tl8,
                                                       unsigned char* __restrict__ ve8) {
  int b = blockIdx.x, hz = blockIdx.y, tid = threadIdx.x;
  bool isV = hz < 4;
  int h2 = isV ? hz : hz - 4;                  // kstep
  const float* src = isV ? (video + (size_t)b * II * CC) : (text + (size_t)b * T1 * CC);
  int n = isV ? II : T1;

  __shared__ float cache[II][132];   // 104 KB: rows x 128-float chunk (pad 4)
  __shared__ float red[16][128];     // 8 KB
  __shared__ float rn[128];

  // pass 1: coalesced chunk read -> LDS cache + sum of squares over rows
  {
    int c4 = tid & 31, rg = tid >> 5;          // rg 0..15
    const float* p = src + h2 * 128 + c4 * 4;
    float4 s = {0.f, 0.f, 0.f, 0.f};
    for (int i = rg; i < n; i += 16) {
      float4 v = *(const float4*)(p + (size_t)i * CC);
      *(float4*)&cache[i][c4 * 4] = v;
      s.x += v.x * v.x; s.y += v.y * v.y; s.z += v.z * v.z; s.w += v.w * v.w;
    }
    *(float4*)&red[rg][c4 * 4] = s;
  }
  __syncthreads();
  if (tid < 128) {
    float s = 0.f;
#pragma unroll
    for (int g = 0; g < 16; ++g) s += red[g][tid];
    rn[tid] = 1.0f / sqrtf(s);
  }
  __syncthreads();

  // pass 2: build 16-B record slices from the LDS cache, fp8 e4m3.
  // slice (frag f, half h, lane l): row/col = f*16+(l&15),
  // chunk-local channels = (l>>4)*32 + h*16 + {0..15}
  if (isV) {
    for (int S = tid; S < 13 * 128; S += 512) {
      int fb = S >> 7, h = (S >> 6) & 1, lane = S & 63;
      int i = fb * 16 + (lane & 15);
      int kloc = ((lane >> 4) & 3) * 32 + h * 16;
      unsigned int wd[4];
#pragma unroll
      for (int q = 0; q < 4; ++q) {
        f32x4 u = {0.f, 0.f, 0.f, 0.f};
        if (i < II) u = *(const f32x4*)&cache[i][kloc + q * 4];
        f32x4 r = *(const f32x4*)&rn[kloc + q * 4];
        int wv = __builtin_amdgcn_cvt_pk_fp8_f32(u[0] * r[0], u[1] * r[1], 0, 0);
        wv = __builtin_amdgcn_cvt_pk_fp8_f32(u[2] * r[2], u[3] * r[3], wv, 1);
        wd[q] = (unsigned int)wv;
      }
      unsigned char* dst = ve8 + (size_t)b * GRP_STRIDE + h2 * KS_STRIDE +
                           fb * 2048 + h * 1024 + lane * 16;
      *(uint4*)dst = make_uint4(wd[0], wd[1], wd[2], wd[3]);
    }
  } else if (tid < 256) {
    // 2 fa_local x 2 h x 64 lane = 256 slices
    int fa_local = tid >> 7, h = (tid >> 6) & 1, lane = tid & 63;
    int t = fa_local * 16 + (lane & 15);          // 0..31
    int kloc = ((lane >> 4) & 3) * 32 + h * 16;
    unsigned int wd[4];
#pragma unroll
    for (int q = 0; q < 4; ++q) {
      f32x4 u = *(const f32x4*)&cache[1 + t][kloc + q * 4];
      f32x4 r = *(const f32x4*)&rn[kloc + q * 4];
      int wv = __builtin_amdgcn_cvt_pk_fp8_f32(u[0] * r[0], u[1] * r[1], 0, 0);
      wv = __builtin_amdgcn_cvt_pk_fp8_f32(u[2] * r[2], u[3] * r[3], wv, 1);
      wd[q] = (unsigned int)wv;
    }
    int fa = (b & 7) * 2 + fa_local;
    unsigned char* dst = tl8 + (size_t)(b >> 3) * GRP_STRIDE + h2 * KS_STRIDE +
                         fa * 2048 + h * 1024 + lane * 16;
    *(uint4*)dst = make_uint4(wd[0], wd[1], wd[2], wd[3]);
  }
}

typedef __attribute__((address_space(3))) unsigned int lds_u32;
typedef __attribute__((address_space(1))) const unsigned int glb_u32;
__device__ __forceinline__ void gl16(const unsigned char* g, unsigned char* l) {
  __builtin_amdgcn_global_load_lds((glb_u32*)(const void*)g, (lds_u32*)(void*)l, 16, 0, 0);
}

// 1024 blocks x 512 threads. ROUND-7: 2 blocks/CU. LDS = ring-2 x (A 8 frags
// 16KB + B 12 frags 24KB) = exactly 80 KB (smax overlaid on As post-loop);
// B frag 12 read direct from global (L2-resident) by the wn==0 waves at phase
// top. launch_bounds(512,4): 128-reg cap; register structure kept lean (acc 64
// AGPR + aop 32 + ONE bop live at a time) so no spill (round-5 lesson: the cap
// only spills when cross-phase reg state is added). Drain-per-phase vmcnt(0)
// is now hidden by the co-resident block (4 waves/SIMD).
__global__ __launch_bounds__(512, 4) void sim_kernel(const unsigned char* __restrict__ tl8,
                                                     const unsigned char* __restrict__ ve8,
                                                     const int* __restrict__ mask,
                                                     float* __restrict__ tti) {
  int L = blockIdx.x;
  int xcd = L & 7;
  int idx = L >> 3;              // 0..127
  int y = xcd * 8 + (idx & 7);   // each XCD owns 8 consecutive y's
  int xcb = idx >> 3;            // 0..15 : 4 batch-x per block

  int tid = threadIdx.x;
  int w = tid >> 6, lane = tid & 63;
  int wm = w >> 2;               // 0..1 : rows wm*64..+64 (4 frags)
  int wn = w & 3;                // col frags wn, wn+4, wn+8 (+12 if wn==0)

  __shared__ __attribute__((aligned(16))) unsigned char As[2][8 * 2048];   // 32KB
  __shared__ __attribute__((aligned(16))) unsigned char Bs[2][12 * 2048];  // 48KB
  float* smax = (float*)&As[0][0];   // overlaid post-loop (2 KB)

  const unsigned char* Abase =
      tl8 + (size_t)(xcb >> 1) * GRP_STRIDE + (size_t)(xcb & 1) * 8 * 2048;
  const unsigned char* Bbase = ve8 + (size_t)y * GRP_STRIDE;

  // 40 gl16 units per kstep: 0..15 = A (fa=u>>1, h=u&1), 16..39 = B frags 0..11.
  // 5 per wave, uniform.
#define STG(s_) do {                                                          \
    int slot_ = (s_) & 1;                                                     \
    _Pragma("unroll")                                                         \
    for (int r_ = 0; r_ < 5; ++r_) {                                          \
      int g_ = w * 5 + r_;                                                    \
      if (g_ < 16) {                                                          \
        int fa_ = g_ >> 1, h_ = g_ & 1;                                       \
        const unsigned char* src_ =                                           \
            Abase + (size_t)(s_) * KS_STRIDE + fa_ * 2048 + h_ * 1024 + lane * 16; \
        gl16(src_, &As[slot_][(fa_ * 2 + h_) * 1024 + lane * 16]);            \
      } else {                                                                \
        int gb_ = g_ - 16;                                                    \
        int fb_ = gb_ >> 1, h_ = gb_ & 1;                                     \
        const unsigned char* src_ =                                           \
            Bbase + (size_t)(s_) * KS_STRIDE + fb_ * 2048 + h_ * 1024 + lane * 16; \
        gl16(src_, &Bs[slot_][(fb_ * 2 + h_) * 1024 + lane * 16]);            \
      }                                                                       \
    }                                                                         \
  } while (0)

  // KCOMPUTE: frag-12 (global, wn==0 only) issued FIRST so its latency hides
  // under the ds_reads + first 12 MFMAs. bop loaded one frag at a time.
#define KCOMPUTE(slot_, s_, F12_) do {                                        \
    i32x4 g0_ = {0, 0, 0, 0}, g1_ = {0, 0, 0, 0};                             \
    if (F12_) {                                                               \
      const unsigned char* p_ =                                               \
          Bbase + (size_t)(s_) * KS_STRIDE + 12 * 2048 + lane * 16;           \
      g0_ = *(const i32x4*)p_;                                                \
      g1_ = *(const i32x4*)(p_ + 1024);                                       \
    }                                                                         \
    i32x8 aop_[4];                                                            \
    _Pragma("unroll")                                                         \
    for (int ma_ = 0; ma_ < 4; ++ma_) {                                       \
      i32x4 h0_ = *(const i32x4*)&As[slot_][((wm * 4 + ma_) * 2) * 1024 + lane * 16]; \
      i32x4 h1_ = *(const i32x4*)&As[slot_][((wm * 4 + ma_) * 2 + 1) * 1024 + lane * 16]; \
      aop_[ma_] = __builtin_shufflevector(h0_, h1_, 0, 1, 2, 3, 4, 5, 6, 7);  \
    }                                                                         \
    __builtin_amdgcn_s_setprio(1);                                            \
    _Pragma("unroll")                                                         \
    for (int nb_ = 0; nb_ < 3; ++nb_) {                                       \
      int fb_ = wn + 4 * nb_;                                                 \
      i32x4 h0_ = *(const i32x4*)&Bs[slot_][(fb_ * 2) * 1024 + lane * 16];    \
      i32x4 h1_ = *(const i32x4*)&Bs[slot_][(fb_ * 2 + 1) * 1024 + lane * 16]; \
      i32x8 bop_ = __builtin_shufflevector(h0_, h1_, 0, 1, 2, 3, 4, 5, 6, 7); \
      _Pragma("unroll")                                                       \
      for (int ma_ = 0; ma_ < 4; ++ma_)                                       \
        acc[ma_][nb_] = __builtin_amdgcn_mfma_scale_f32_16x16x128_f8f6f4(     \
            aop_[ma_], bop_, acc[ma_][nb_], 0, 0,                             \
            0, 0x7F7F7F7F, 0, 0x7F7F7F7F);                                    \
    }                                                                         \
    if (F12_) {                                                               \
      i32x8 bop_ = __builtin_shufflevector(g0_, g1_, 0, 1, 2, 3, 4, 5, 6, 7); \
      _Pragma("unroll")                                                       \
      for (int ma_ = 0; ma_ < 4; ++ma_)                                       \
        acc[ma_][3] = __builtin_amdgcn_mfma_scale_f32_16x16x128_f8f6f4(       \
            aop_[ma_], bop_, acc[ma_][3], 0, 0,                               \
            0, 0x7F7F7F7F, 0, 0x7F7F7F7F);                                    \
    }                                                                         \
    __builtin_amdgcn_s_setprio(0);                                            \
  } while (0)

  f32x4 acc[4][4] = {};

  // prologue: kstep 0 -> slot 0
  STG(0);
  asm volatile("s_waitcnt vmcnt(0)" ::: "memory");
  __builtin_amdgcn_s_barrier();

  // s=0: stage kstep1 -> slot1, compute slot0
  STG(1);
  if (wn == 0) KCOMPUTE(0, 0, 1); else KCOMPUTE(0, 0, 0);
  asm volatile("s_waitcnt vmcnt(0)" ::: "memory");
  __builtin_amdgcn_s_barrier();
  // s=1: stage kstep2 -> slot0, compute slot1
  STG(2);
  if (wn == 0) KCOMPUTE(1, 1, 1); else KCOMPUTE(1, 1, 0);
  asm volatile("s_waitcnt vmcnt(0)" ::: "memory");
  __builtin_amdgcn_s_barrier();
  // s=2: stage kstep3 -> slot1, compute slot0
  STG(3);
  if (wn == 0) KCOMPUTE(0, 2, 1); else KCOMPUTE(0, 2, 0);
  asm volatile("s_waitcnt vmcnt(0)" ::: "memory");
  __builtin_amdgcn_s_barrier();
  // s=3: compute slot1
  if (wn == 0) KCOMPUTE(1, 3, 1); else KCOMPUTE(1, 3, 0);
#undef STG
#undef KCOMPUTE

  // ---- fused epilogue: max over i (i<197), masked mean over t -> tti ----
  int col = lane & 15, gq = lane >> 4;
  int nfrag = (wn == 0) ? 4 : 3;
  bool valid[4];
#pragma unroll
  for (int nb = 0; nb < 4; ++nb) {
    int fb = wn + 4 * nb;
    valid[nb] = (nb < nfrag) && (fb * 16 + col < II);
  }

  float mx[4][4];
#pragma unroll
  for (int ma = 0; ma < 4; ++ma)
#pragma unroll
    for (int reg = 0; reg < 4; ++reg) {
      float m = -FLT_MAX;
#pragma unroll
      for (int nb = 0; nb < 4; ++nb)
        if (valid[nb]) m = fmaxf(m, acc[ma][nb][reg]);
      mx[ma][reg] = m;
    }
#pragma unroll
  for (int st = 1; st <= 8; st <<= 1)
#pragma unroll
    for (int ma = 0; ma < 4; ++ma)
#pragma unroll
      for (int reg = 0; reg < 4; ++reg)
        mx[ma][reg] = fmaxf(mx[ma][reg], __shfl_xor(mx[ma][reg], st));

  __syncthreads();   // all waves past the K-loop before smax overlays As[0]
  if (col == 0) {
#pragma unroll
    for (int ma = 0; ma < 4; ++ma)
#pragma unroll
      for (int reg = 0; reg < 4; ++reg)
        smax[wn * 128 + wm * 64 + ma * 16 + gq * 4 + reg] = mx[ma][reg];
  }
  __syncthreads();

  if (tid < 128) {
    int r = tid;                       // row = x_local*32 + t
    float m = fmaxf(fmaxf(smax[r], smax[128 + r]),
                    fmaxf(smax[256 + r], smax[384 + r]));
    int x = xcb * 4 + (r >> 5), tt = r & 31;
    int mk = mask[x * T1 + 1 + tt];
    float num = mk ? m * TEMP : 0.f;
    float cnt = mk ? 1.f : 0.f;
#pragma unroll
    for (int st = 1; st < 32; st <<= 1) {
      num += __shfl_xor(num, st);
      cnt += __shfl_xor(cnt, st);
    }
    if (tt == 0) tti[x * 64 + y] = num / fmaxf(cnt, 1e-6f);
  }
}

// 1 block x 1024 threads: 16 threads per row x, each sums 4 y's.
__global__ void loss_kernel(const float* __restrict__ tti, float* __restrict__ out) {
  __shared__ float lxs[64];
  int tid = threadIdx.x;
  int x = tid >> 4, q = tid & 15;
  float4 v = *(const float4*)&tti[x * 64 + q * 4];
  float den = expf(v.x) + expf(v.y) + expf(v.z) + expf(v.w);
#pragma unroll
  for (int st = 1; st < 16; st <<= 1) den += __shfl_xor(den, st);
  if (q == 0) {
    float pos = expf(tti[x * 64 + x]);
    lxs[x] = -logf(pos / den + 1e-20f);
  }
  __syncthreads();
  if (tid < 64) {
    float lx = lxs[tid];
#pragma unroll
    for (int s = 1; s < 64; s <<= 1) lx += __shfl_xor(lx, s);
    if (tid == 0) out[0] = lx * (1.0f / 64.0f);
  }
}

extern "C" void kernel_launch(void* const* d_in, const int* in_sizes, int n_in,
                              void* d_out, int out_size, void* d_ws, size_t ws_size,
                              hipStream_t stream) {
  const float* text = (const float*)d_in[0];   // [64][33][512] f32
  const float* video = (const float*)d_in[1];  // [64][197][512] f32
  const int* mask = (const int*)d_in[2];       // [64][33] i32
  float* out = (float*)d_out;

  char* ws = (char*)d_ws;
  unsigned char* tl8 = (unsigned char*)(ws + TL_OFF);
  unsigned char* ve8 = (unsigned char*)(ws + VE_OFF);
  float* tti = (float*)(ws + TTI_OFF);

  hipLaunchKernelGGL(norm_all_kernel, dim3(BB, 8), dim3(512), 0, stream, text, video, tl8, ve8);
  hipLaunchKernelGGL(sim_kernel, dim3(1024), dim3(512), 0, stream, tl8, ve8, mask, tti);
  hipLaunchKernelGGL(loss_kernel, dim3(1), dim3(1024), 0, stream, tti, out);
}

// Round 8
// 43.998 us; speedup vs baseline: 1.6092x; 1.6092x over previous
//
#include <hip/hip_runtime.h>
#include <hip/hip_bf16.h>
#include <float.h>
#include <math.h>

#define BB 64
#define T1 33
#define TT 32
#define II 197
#define CC 512
#define TEMP 0.07f

typedef float f32x4 __attribute__((ext_vector_type(4)));
typedef int i32x4 __attribute__((ext_vector_type(4)));
typedef int i32x8 __attribute__((ext_vector_type(8)));

// ---- workspace layout (bytes) ----
// Frag records for mfma_scale_f32_16x16x128_f8f6f4 (fp8): per frag per kstep,
// 2048 B = [half h 0..1][lane 0..63][16 B]; element (row/col = lane&15,
// k = ks*128 + (lane>>4)*32 + h*16 + j).
// tl8: [xc8 8][ks 4][fa 16] records  (1 MB)   A: text rows r=fa*16+(lane&15)
// ve8: [y 64][ks 4][fb 16] records  (8 MB)   B: cols  i=fb*16+(lane&15); fb<=12 written
// tti: [64 x][64 y] f32
#define TL_OFF  0
#define VE_OFF  (1 << 20)                  // 1 MB
#define TTI_OFF ((1 << 20) + (8 << 20))    // 9 MB
#define KS_STRIDE   32768                  // 16 frags * 2048
#define GRP_STRIDE  131072                 // 4 ks * KS_STRIDE

// grid (64, 8): hz 0..3 = video c-chunks (= ksteps), hz 4..7 = text c-chunks.
// 512 threads. Pass 1 caches the block's 100 KB row-chunk in LDS; pass 2
// builds fp8 records from LDS (inputs read from HBM exactly once, coalesced).
__global__ __launch_bounds__(512) void norm_all_kernel(const float* __restrict__ text,
                                                       const float* __restrict__ video,
                                                       unsigned char* __restrict__ tl8,
                                                       unsigned char* __restrict__ ve8) {
  int b = blockIdx.x, hz = blockIdx.y, tid = threadIdx.x;
  bool isV = hz < 4;
  int h2 = isV ? hz : hz - 4;                  // kstep
  const float* src = isV ? (video + (size_t)b * II * CC) : (text + (size_t)b * T1 * CC);
  int n = isV ? II : T1;

  __shared__ float cache[II][132];   // 104 KB: rows x 128-float chunk (pad 4)
  __shared__ float red[16][128];     // 8 KB
  __shared__ float rn[128];

  // pass 1: coalesced chunk read -> LDS cache + sum of squares over rows
  {
    int c4 = tid & 31, rg = tid >> 5;          // rg 0..15
    const float* p = src + h2 * 128 + c4 * 4;
    float4 s = {0.f, 0.f, 0.f, 0.f};
    for (int i = rg; i < n; i += 16) {
      float4 v = *(const float4*)(p + (size_t)i * CC);
      *(float4*)&cache[i][c4 * 4] = v;
      s.x += v.x * v.x; s.y += v.y * v.y; s.z += v.z * v.z; s.w += v.w * v.w;
    }
    *(float4*)&red[rg][c4 * 4] = s;
  }
  __syncthreads();
  if (tid < 128) {
    float s = 0.f;
#pragma unroll
    for (int g = 0; g < 16; ++g) s += red[g][tid];
    rn[tid] = 1.0f / sqrtf(s);
  }
  __syncthreads();

  // pass 2: build 16-B record slices from the LDS cache, fp8 e4m3.
  // slice (frag f, half h, lane l): row/col = f*16+(l&15),
  // chunk-local channels = (l>>4)*32 + h*16 + {0..15}
  if (isV) {
    for (int S = tid; S < 13 * 128; S += 512) {
      int fb = S >> 7, h = (S >> 6) & 1, lane = S & 63;
      int i = fb * 16 + (lane & 15);
      int kloc = ((lane >> 4) & 3) * 32 + h * 16;
      unsigned int wd[4];
#pragma unroll
      for (int q = 0; q < 4; ++q) {
        f32x4 u = {0.f, 0.f, 0.f, 0.f};
        if (i < II) u = *(const f32x4*)&cache[i][kloc + q * 4];
        f32x4 r = *(const f32x4*)&rn[kloc + q * 4];
        int wv = __builtin_amdgcn_cvt_pk_fp8_f32(u[0] * r[0], u[1] * r[1], 0, 0);
        wv = __builtin_amdgcn_cvt_pk_fp8_f32(u[2] * r[2], u[3] * r[3], wv, 1);
        wd[q] = (unsigned int)wv;
      }
      unsigned char* dst = ve8 + (size_t)b * GRP_STRIDE + h2 * KS_STRIDE +
                           fb * 2048 + h * 1024 + lane * 16;
      *(uint4*)dst = make_uint4(wd[0], wd[1], wd[2], wd[3]);
    }
  } else if (tid < 256) {
    // 2 fa_local x 2 h x 64 lane = 256 slices
    int fa_local = tid >> 7, h = (tid >> 6) & 1, lane = tid & 63;
    int t = fa_local * 16 + (lane & 15);          // 0..31
    int kloc = ((lane >> 4) & 3) * 32 + h * 16;
    unsigned int wd[4];
#pragma unroll
    for (int q = 0; q < 4; ++q) {
      f32x4 u = *(const f32x4*)&cache[1 + t][kloc + q * 4];
      f32x4 r = *(const f32x4*)&rn[kloc + q * 4];
      int wv = __builtin_amdgcn_cvt_pk_fp8_f32(u[0] * r[0], u[1] * r[1], 0, 0);
      wv = __builtin_amdgcn_cvt_pk_fp8_f32(u[2] * r[2], u[3] * r[3], wv, 1);
      wd[q] = (unsigned int)wv;
    }
    int fa = (b & 7) * 2 + fa_local;
    unsigned char* dst = tl8 + (size_t)(b >> 3) * GRP_STRIDE + h2 * KS_STRIDE +
                         fa * 2048 + h * 1024 + lane * 16;
    *(uint4*)dst = make_uint4(wd[0], wd[1], wd[2], wd[3]);
  }
}

typedef __attribute__((address_space(3))) unsigned int lds_u32;
typedef __attribute__((address_space(1))) const unsigned int glb_u32;
__device__ __forceinline__ void gl16(const unsigned char* g, unsigned char* l) {
  __builtin_amdgcn_global_load_lds((glb_u32*)(const void*)g, (lds_u32*)(void*)l, 16, 0, 0);
}

// ROUND-8: 2048 blocks x 512 threads, 2 blocks/CU. Each block: 64 rows
// (2 batch-x) x 208 cols, K=512 as 4 ksteps of 128 (mfma_scale 16x16x128
// fp8, scales=1.0). Halved row-tile halves the accumulator: acc[2][4] =
// 32 VGPR; live set ~90 regs fits the (512,4) 128-reg cap WITHOUT spilling
// (rounds 5/7: acc[4][4]=64 under the same cap always spilled). All 13 B
// col-frags staged in LDS (no divergent global frag-12 read, no cross-phase
// reg state). LDS = ring-2 x (A 4 frags 8KB + B 13 frags 26KB) = 68 KB ->
// 2 blocks/CU, 4 waves/SIMD: co-resident block hides the per-phase vmcnt(0)
// drain. B L2 reads double vs round 6, but per-XCD working set (tl8 1MB +
// 8 y's of ve8 1MB) stays L2-resident. Col-frag f -> wave wn=f%4 (4/3/3/3).
__global__ __launch_bounds__(512, 4) void sim_kernel(const unsigned char* __restrict__ tl8,
                                                     const unsigned char* __restrict__ ve8,
                                                     const int* __restrict__ mask,
                                                     float* __restrict__ tti) {
  int L = blockIdx.x;
  int xcd = L & 7;
  int idx = L >> 3;              // 0..255
  int y = xcd * 8 + (idx & 7);   // each XCD owns 8 consecutive y's
  int xcb = idx >> 3;            // 0..31 : 2 batch-x per block (64 rows)

  int tid = threadIdx.x;
  int w = tid >> 6, lane = tid & 63;
  int wm = w >> 2;               // 0..1 : rows wm*32..+32 (2 frags)
  int wn = w & 3;                // col frags wn, wn+4, wn+8 (+12 if wn==0)

  __shared__ __attribute__((aligned(16))) unsigned char As[2][4 * 2048];   // 16KB
  __shared__ __attribute__((aligned(16))) unsigned char Bs[2][13 * 2048];  // 52KB
  float* smax = (float*)&As[0][0];   // overlaid post-loop (1 KB)

  const unsigned char* Abase =
      tl8 + (size_t)(xcb >> 2) * GRP_STRIDE + (size_t)(xcb & 3) * 4 * 2048;
  const unsigned char* Bbase = ve8 + (size_t)y * GRP_STRIDE;

  // 34 gl16 units per kstep: 0..7 = A (fa=u>>1, h=u&1), 8..33 = B frags 0..12.
#define STG(s_) do {                                                          \
    int slot_ = (s_) & 1;                                                     \
    _Pragma("unroll")                                                         \
    for (int r_ = 0; r_ < 5; ++r_) {                                          \
      int u_ = w * 5 + r_;                                                    \
      if (u_ < 8) {                                                           \
        int fa_ = u_ >> 1, h_ = u_ & 1;                                       \
        const unsigned char* src_ =                                           \
            Abase + (size_t)(s_) * KS_STRIDE + fa_ * 2048 + h_ * 1024 + lane * 16; \
        gl16(src_, &As[slot_][(fa_ * 2 + h_) * 1024 + lane * 16]);            \
      } else if (u_ < 34) {                                                   \
        int gb_ = u_ - 8;                                                     \
        int fb_ = gb_ >> 1, h_ = gb_ & 1;                                     \
        const unsigned char* src_ =                                           \
            Bbase + (size_t)(s_) * KS_STRIDE + fb_ * 2048 + h_ * 1024 + lane * 16; \
        gl16(src_, &Bs[slot_][(fb_ * 2 + h_) * 1024 + lane * 16]);            \
      }                                                                       \
    }                                                                         \
  } while (0)

  // bop loaded one frag at a time; frag 12 (wn==0) from LDS like the rest.
#define KCOMPUTE(slot_) do {                                                  \
    i32x8 aop_[2];                                                            \
    _Pragma("unroll")                                                         \
    for (int ma_ = 0; ma_ < 2; ++ma_) {                                       \
      i32x4 h0_ = *(const i32x4*)&As[slot_][((wm * 2 + ma_) * 2) * 1024 + lane * 16]; \
      i32x4 h1_ = *(const i32x4*)&As[slot_][((wm * 2 + ma_) * 2 + 1) * 1024 + lane * 16]; \
      aop_[ma_] = __builtin_shufflevector(h0_, h1_, 0, 1, 2, 3, 4, 5, 6, 7);  \
    }                                                                         \
    __builtin_amdgcn_s_setprio(1);                                            \
    _Pragma("unroll")                                                         \
    for (int nb_ = 0; nb_ < 3; ++nb_) {                                       \
      int fb_ = wn + 4 * nb_;                                                 \
      i32x4 h0_ = *(const i32x4*)&Bs[slot_][(fb_ * 2) * 1024 + lane * 16];    \
      i32x4 h1_ = *(const i32x4*)&Bs[slot_][(fb_ * 2 + 1) * 1024 + lane * 16]; \
      i32x8 bop_ = __builtin_shufflevector(h0_, h1_, 0, 1, 2, 3, 4, 5, 6, 7); \
      _Pragma("unroll")                                                       \
      for (int ma_ = 0; ma_ < 2; ++ma_)                                       \
        acc[ma_][nb_] = __builtin_amdgcn_mfma_scale_f32_16x16x128_f8f6f4(     \
            aop_[ma_], bop_, acc[ma_][nb_], 0, 0,                             \
            0, 0x7F7F7F7F, 0, 0x7F7F7F7F);                                    \
    }                                                                         \
    if (wn == 0) {                                                            \
      i32x4 h0_ = *(const i32x4*)&Bs[slot_][(12 * 2) * 1024 + lane * 16];     \
      i32x4 h1_ = *(const i32x4*)&Bs[slot_][(12 * 2 + 1) * 1024 + lane * 16]; \
      i32x8 bop_ = __builtin_shufflevector(h0_, h1_, 0, 1, 2, 3, 4, 5, 6, 7); \
      _Pragma("unroll")                                                       \
      for (int ma_ = 0; ma_ < 2; ++ma_)                                       \
        acc[ma_][3] = __builtin_amdgcn_mfma_scale_f32_16x16x128_f8f6f4(       \
            aop_[ma_], bop_, acc[ma_][3], 0, 0,                               \
            0, 0x7F7F7F7F, 0, 0x7F7F7F7F);                                    \
    }                                                                         \
    __builtin_amdgcn_s_setprio(0);                                            \
  } while (0)

  f32x4 acc[2][4] = {};

  // prologue: kstep 0 -> slot 0
  STG(0);
  asm volatile("s_waitcnt vmcnt(0)" ::: "memory");
  __builtin_amdgcn_s_barrier();

  // s=0: stage kstep1 -> slot1, compute slot0
  STG(1);
  KCOMPUTE(0);
  asm volatile("s_waitcnt vmcnt(0)" ::: "memory");
  __builtin_amdgcn_s_barrier();
  // s=1: stage kstep2 -> slot0, compute slot1
  STG(2);
  KCOMPUTE(1);
  asm volatile("s_waitcnt vmcnt(0)" ::: "memory");
  __builtin_amdgcn_s_barrier();
  // s=2: stage kstep3 -> slot1, compute slot0
  STG(3);
  KCOMPUTE(0);
  asm volatile("s_waitcnt vmcnt(0)" ::: "memory");
  __builtin_amdgcn_s_barrier();
  // s=3: compute slot1
  KCOMPUTE(1);
#undef STG
#undef KCOMPUTE

  // ---- fused epilogue: max over i (i<197), masked mean over t -> tti ----
  int col = lane & 15, gq = lane >> 4;
  int nfrag = (wn == 0) ? 4 : 3;
  bool valid[4];
#pragma unroll
  for (int nb = 0; nb < 4; ++nb) {
    int fb = wn + 4 * nb;
    valid[nb] = (nb < nfrag) && (fb * 16 + col < II);
  }

  float mx[2][4];
#pragma unroll
  for (int ma = 0; ma < 2; ++ma)
#pragma unroll
    for (int reg = 0; reg < 4; ++reg) {
      float m = -FLT_MAX;
#pragma unroll
      for (int nb = 0; nb < 4; ++nb)
        if (valid[nb]) m = fmaxf(m, acc[ma][nb][reg]);
      mx[ma][reg] = m;
    }
#pragma unroll
  for (int st = 1; st <= 8; st <<= 1)
#pragma unroll
    for (int ma = 0; ma < 2; ++ma)
#pragma unroll
      for (int reg = 0; reg < 4; ++reg)
        mx[ma][reg] = fmaxf(mx[ma][reg], __shfl_xor(mx[ma][reg], st));

  __syncthreads();   // all waves past the K-loop before smax overlays As[0]
  if (col == 0) {
#pragma unroll
    for (int ma = 0; ma < 2; ++ma)
#pragma unroll
      for (int reg = 0; reg < 4; ++reg)
        smax[wn * 64 + wm * 32 + ma * 16 + gq * 4 + reg] = mx[ma][reg];
  }
  __syncthreads();

  if (tid < 64) {
    int r = tid;                       // row = x_local*32 + t (x_local 0..1)
    float m = fmaxf(fmaxf(smax[r], smax[64 + r]),
                    fmaxf(smax[128 + r], smax[192 + r]));
    int x = xcb * 2 + (r >> 5), tt = r & 31;
    int mk = mask[x * T1 + 1 + tt];
    float num = mk ? m * TEMP : 0.f;
    float cnt = mk ? 1.f : 0.f;
#pragma unroll
    for (int st = 1; st < 32; st <<= 1) {
      num += __shfl_xor(num, st);
      cnt += __shfl_xor(cnt, st);
    }
    if (tt == 0) tti[x * 64 + y] = num / fmaxf(cnt, 1e-6f);
  }
}

// 1 block x 1024 threads: 16 threads per row x, each sums 4 y's.
__global__ void loss_kernel(const float* __restrict__ tti, float* __restrict__ out) {
  __shared__ float lxs[64];
  int tid = threadIdx.x;
  int x = tid >> 4, q = tid & 15;
  float4 v = *(const float4*)&tti[x * 64 + q * 4];
  float den = expf(v.x) + expf(v.y) + expf(v.z) + expf(v.w);
#pragma unroll
  for (int st = 1; st < 16; st <<= 1) den += __shfl_xor(den, st);
  if (q == 0) {
    float pos = expf(tti[x * 64 + x]);
    lxs[x] = -logf(pos / den + 1e-20f);
  }
  __syncthreads();
  if (tid < 64) {
    float lx = lxs[tid];
#pragma unroll
    for (int s = 1; s < 64; s <<= 1) lx += __shfl_xor(lx, s);
    if (tid == 0) out[0] = lx * (1.0f / 64.0f);
  }
}

extern "C" void kernel_launch(void* const* d_in, const int* in_sizes, int n_in,
                              void* d_out, int out_size, void* d_ws, size_t ws_size,
                              hipStream_t stream) {
  const float* text = (const float*)d_in[0];   // [64][33][512] f32
  const float* video = (const float*)d_in[1];  // [64][197][512] f32
  const int* mask = (const int*)d_in[2];       // [64][33] i32
  float* out = (float*)d_out;

  char* ws = (char*)d_ws;
  unsigned char* tl8 = (unsigned char*)(ws + TL_OFF);
  unsigned char* ve8 = (unsigned char*)(ws + VE_OFF);
  float* tti = (float*)(ws + TTI_OFF);

  hipLaunchKernelGGL(norm_all_kernel, dim3(BB, 8), dim3(512), 0, stream, text, video, tl8, ve8);
  hipLaunchKernelGGL(sim_kernel, dim3(2048), dim3(512), 0, stream, tl8, ve8, mask, tti);
  hipLaunchKernelGGL(loss_kernel, dim3(1), dim3(1024), 0, stream, tti, out);
}

// Round 9
// 41.868 us; speedup vs baseline: 1.6911x; 1.0509x over previous
//
#include <hip/hip_runtime.h>
#include <hip/hip_bf16.h>
#include <float.h>
#include <math.h>

#define BB 64
#define T1 33
#define TT 32
#define II 197
#define CC 512
#define TEMP 0.07f

typedef float f32x4 __attribute__((ext_vector_type(4)));
typedef int i32x4 __attribute__((ext_vector_type(4)));
typedef int i32x8 __attribute__((ext_vector_type(8)));

// ---- workspace layout (bytes) ----
// Frag records for mfma_scale_f32_16x16x128_f8f6f4 (fp8): per frag per kstep,
// 2048 B = [half h 0..1][lane 0..63][16 B]; element (row/col = lane&15,
// k = ks*128 + (lane>>4)*32 + h*16 + j).
// tl8: [xc8 8][ks 4][fa 16] records  (1 MB)   A: text rows r=fa*16+(lane&15)
// ve8: [y 64][ks 4][fb 16] records  (8 MB)   B: cols  i=fb*16+(lane&15); fb<=12 written
// tti: [64 x][64 y] f32
#define TL_OFF  0
#define VE_OFF  (1 << 20)                  // 1 MB
#define TTI_OFF ((1 << 20) + (8 << 20))    // 9 MB
#define KS_STRIDE   32768                  // 16 frags * 2048
#define GRP_STRIDE  131072                 // 4 ks * KS_STRIDE

// grid (64, 8): hz 0..3 = video c-chunks (= ksteps), hz 4..7 = text c-chunks.
// 512 threads. Pass 1 caches the block's 100 KB row-chunk in LDS; pass 2
// builds fp8 records from LDS (inputs read from HBM exactly once, coalesced).
__global__ __launch_bounds__(512) void norm_all_kernel(const float* __restrict__ text,
                                                       const float* __restrict__ video,
                                                       unsigned char* __restrict__ tl8,
                                                       unsigned char* __restrict__ ve8) {
  int b = blockIdx.x, hz = blockIdx.y, tid = threadIdx.x;
  bool isV = hz < 4;
  int h2 = isV ? hz : hz - 4;                  // kstep
  const float* src = isV ? (video + (size_t)b * II * CC) : (text + (size_t)b * T1 * CC);
  int n = isV ? II : T1;

  __shared__ float cache[II][132];   // 104 KB: rows x 128-float chunk (pad 4)
  __shared__ float red[16][128];     // 8 KB
  __shared__ float rn[128];

  // pass 1: coalesced chunk read -> LDS cache + sum of squares over rows
  {
    int c4 = tid & 31, rg = tid >> 5;          // rg 0..15
    const float* p = src + h2 * 128 + c4 * 4;
    float4 s = {0.f, 0.f, 0.f, 0.f};
    for (int i = rg; i < n; i += 16) {
      float4 v = *(const float4*)(p + (size_t)i * CC);
      *(float4*)&cache[i][c4 * 4] = v;
      s.x += v.x * v.x; s.y += v.y * v.y; s.z += v.z * v.z; s.w += v.w * v.w;
    }
    *(float4*)&red[rg][c4 * 4] = s;
  }
  __syncthreads();
  if (tid < 128) {
    float s = 0.f;
#pragma unroll
    for (int g = 0; g < 16; ++g) s += red[g][tid];
    rn[tid] = 1.0f / sqrtf(s);
  }
  __syncthreads();

  // pass 2: build 16-B record slices from the LDS cache, fp8 e4m3.
  // slice (frag f, half h, lane l): row/col = f*16+(l&15),
  // chunk-local channels = (l>>4)*32 + h*16 + {0..15}
  if (isV) {
    for (int S = tid; S < 13 * 128; S += 512) {
      int fb = S >> 7, h = (S >> 6) & 1, lane = S & 63;
      int i = fb * 16 + (lane & 15);
      int kloc = ((lane >> 4) & 3) * 32 + h * 16;
      unsigned int wd[4];
#pragma unroll
      for (int q = 0; q < 4; ++q) {
        f32x4 u = {0.f, 0.f, 0.f, 0.f};
        if (i < II) u = *(const f32x4*)&cache[i][kloc + q * 4];
        f32x4 r = *(const f32x4*)&rn[kloc + q * 4];
        int wv = __builtin_amdgcn_cvt_pk_fp8_f32(u[0] * r[0], u[1] * r[1], 0, 0);
        wv = __builtin_amdgcn_cvt_pk_fp8_f32(u[2] * r[2], u[3] * r[3], wv, 1);
        wd[q] = (unsigned int)wv;
      }
      unsigned char* dst = ve8 + (size_t)b * GRP_STRIDE + h2 * KS_STRIDE +
                           fb * 2048 + h * 1024 + lane * 16;
      *(uint4*)dst = make_uint4(wd[0], wd[1], wd[2], wd[3]);
    }
  } else if (tid < 256) {
    // 2 fa_local x 2 h x 64 lane = 256 slices
    int fa_local = tid >> 7, h = (tid >> 6) & 1, lane = tid & 63;
    int t = fa_local * 16 + (lane & 15);          // 0..31
    int kloc = ((lane >> 4) & 3) * 32 + h * 16;
    unsigned int wd[4];
#pragma unroll
    for (int q = 0; q < 4; ++q) {
      f32x4 u = *(const f32x4*)&cache[1 + t][kloc + q * 4];
      f32x4 r = *(const f32x4*)&rn[kloc + q * 4];
      int wv = __builtin_amdgcn_cvt_pk_fp8_f32(u[0] * r[0], u[1] * r[1], 0, 0);
      wv = __builtin_amdgcn_cvt_pk_fp8_f32(u[2] * r[2], u[3] * r[3], wv, 1);
      wd[q] = (unsigned int)wv;
    }
    int fa = (b & 7) * 2 + fa_local;
    unsigned char* dst = tl8 + (size_t)(b >> 3) * GRP_STRIDE + h2 * KS_STRIDE +
                         fa * 2048 + h * 1024 + lane * 16;
    *(uint4*)dst = make_uint4(wd[0], wd[1], wd[2], wd[3]);
  }
}

// ROUND-9: zero-LDS direct-to-register sim. 2048 blocks x 512 threads.
// Each block: 64 rows (2 batch-x) x 208 cols, K=512 as 4 ksteps of 128
// (mfma_scale 16x16x128 fp8, scales=1.0). Rationale: round-8's LDS pipe
// carried staging DMA (136 KB/block) + replicated frag reads (336 KB/block)
// ~= 16-20 us/CU, the dominant pipe. Operands are L2-resident (per XCD:
// tl8 1MB + 8 y-slices 1MB) and the per-kstep working set (A 8KB + B 26KB)
// fits 32KB L1, which absorbs the wave replication. So: every wave loads
// its fragments global->reg directly; NO LDS staging, NO barriers in the
// K-loop, no vmcnt drains. #pragma unroll 1 on the kstep loop keeps the
// live set bounded (acc 32 + aop 16 + transient bop + addr ~= 80 regs
// under the (512,4) 128-reg cap -- full unroll would hoist 4 ksteps of
// loads and spill, per rounds 5/7). Wave map: wm=w&1, wn=w>>1 puts the
// two frag-12 waves (wn==0) on different SIMDs (7/7/6/6 MFMA balance).
__global__ __launch_bounds__(512, 4) void sim_kernel(const unsigned char* __restrict__ tl8,
                                                     const unsigned char* __restrict__ ve8,
                                                     const int* __restrict__ mask,
                                                     float* __restrict__ tti) {
  int L = blockIdx.x;
  int xcd = L & 7;
  int idx = L >> 3;              // 0..255
  int y = xcd * 8 + (idx & 7);   // each XCD owns 8 consecutive y's
  int xcb = idx >> 3;            // 0..31 : 2 batch-x per block (64 rows)

  int tid = threadIdx.x;
  int w = tid >> 6, lane = tid & 63;
  int wm = w & 1;                // rows wm*32..+32 (2 frags)
  int wn = w >> 1;               // col frags wn, wn+4, wn+8 (+12 if wn==0)

  __shared__ float smax[4 * 64]; // [wn][row] 1 KB

  const unsigned char* Abase =
      tl8 + (size_t)(xcb >> 2) * GRP_STRIDE + (size_t)(xcb & 3) * 4 * 2048;
  const unsigned char* Bbase = ve8 + (size_t)y * GRP_STRIDE;

  f32x4 acc[2][4] = {};

#pragma unroll 1
  for (int s = 0; s < 4; ++s) {
    const unsigned char* ab = Abase + (size_t)s * KS_STRIDE + lane * 16;
    const unsigned char* bb = Bbase + (size_t)s * KS_STRIDE + lane * 16;

    i32x8 aop[2];
#pragma unroll
    for (int ma = 0; ma < 2; ++ma) {
      const unsigned char* p = ab + (wm * 2 + ma) * 2048;
      i32x4 h0 = *(const i32x4*)p;
      i32x4 h1 = *(const i32x4*)(p + 1024);
      aop[ma] = __builtin_shufflevector(h0, h1, 0, 1, 2, 3, 4, 5, 6, 7);
    }

#pragma unroll
    for (int nb = 0; nb < 3; ++nb) {
      int fb = wn + 4 * nb;
      const unsigned char* p = bb + fb * 2048;
      i32x4 h0 = *(const i32x4*)p;
      i32x4 h1 = *(const i32x4*)(p + 1024);
      i32x8 bop = __builtin_shufflevector(h0, h1, 0, 1, 2, 3, 4, 5, 6, 7);
#pragma unroll
      for (int ma = 0; ma < 2; ++ma)
        acc[ma][nb] = __builtin_amdgcn_mfma_scale_f32_16x16x128_f8f6f4(
            aop[ma], bop, acc[ma][nb], 0, 0,
            0, 0x7F7F7F7F, 0, 0x7F7F7F7F);
    }
    if (wn == 0) {
      const unsigned char* p = bb + 12 * 2048;
      i32x4 h0 = *(const i32x4*)p;
      i32x4 h1 = *(const i32x4*)(p + 1024);
      i32x8 bop = __builtin_shufflevector(h0, h1, 0, 1, 2, 3, 4, 5, 6, 7);
#pragma unroll
      for (int ma = 0; ma < 2; ++ma)
        acc[ma][3] = __builtin_amdgcn_mfma_scale_f32_16x16x128_f8f6f4(
            aop[ma], bop, acc[ma][3], 0, 0,
            0, 0x7F7F7F7F, 0, 0x7F7F7F7F);
    }
  }

  // ---- fused epilogue: max over i (i<197), masked mean over t -> tti ----
  int col = lane & 15, gq = lane >> 4;
  int nfrag = (wn == 0) ? 4 : 3;
  bool valid[4];
#pragma unroll
  for (int nb = 0; nb < 4; ++nb) {
    int fb = wn + 4 * nb;
    valid[nb] = (nb < nfrag) && (fb * 16 + col < II);
  }

  float mx[2][4];
#pragma unroll
  for (int ma = 0; ma < 2; ++ma)
#pragma unroll
    for (int reg = 0; reg < 4; ++reg) {
      float m = -FLT_MAX;
#pragma unroll
      for (int nb = 0; nb < 4; ++nb)
        if (valid[nb]) m = fmaxf(m, acc[ma][nb][reg]);
      mx[ma][reg] = m;
    }
#pragma unroll
  for (int st = 1; st <= 8; st <<= 1)
#pragma unroll
    for (int ma = 0; ma < 2; ++ma)
#pragma unroll
      for (int reg = 0; reg < 4; ++reg)
        mx[ma][reg] = fmaxf(mx[ma][reg], __shfl_xor(mx[ma][reg], st));

  if (col == 0) {
#pragma unroll
    for (int ma = 0; ma < 2; ++ma)
#pragma unroll
      for (int reg = 0; reg < 4; ++reg)
        smax[wn * 64 + wm * 32 + ma * 16 + gq * 4 + reg] = mx[ma][reg];
  }
  __syncthreads();

  if (tid < 64) {
    int r = tid;                       // row = x_local*32 + t (x_local 0..1)
    float m = fmaxf(fmaxf(smax[r], smax[64 + r]),
                    fmaxf(smax[128 + r], smax[192 + r]));
    int x = xcb * 2 + (r >> 5), tt = r & 31;
    int mk = mask[x * T1 + 1 + tt];
    float num = mk ? m * TEMP : 0.f;
    float cnt = mk ? 1.f : 0.f;
#pragma unroll
    for (int st = 1; st < 32; st <<= 1) {
      num += __shfl_xor(num, st);
      cnt += __shfl_xor(cnt, st);
    }
    if (tt == 0) tti[x * 64 + y] = num / fmaxf(cnt, 1e-6f);
  }
}

// 1 block x 1024 threads: 16 threads per row x, each sums 4 y's.
__global__ void loss_kernel(const float* __restrict__ tti, float* __restrict__ out) {
  __shared__ float lxs[64];
  int tid = threadIdx.x;
  int x = tid >> 4, q = tid & 15;
  float4 v = *(const float4*)&tti[x * 64 + q * 4];
  float den = expf(v.x) + expf(v.y) + expf(v.z) + expf(v.w);
#pragma unroll
  for (int st = 1; st < 16; st <<= 1) den += __shfl_xor(den, st);
  if (q == 0) {
    float pos = expf(tti[x * 64 + x]);
    lxs[x] = -logf(pos / den + 1e-20f);
  }
  __syncthreads();
  if (tid < 64) {
    float lx = lxs[tid];
#pragma unroll
    for (int s = 1; s < 64; s <<= 1) lx += __shfl_xor(lx, s);
    if (tid == 0) out[0] = lx * (1.0f / 64.0f);
  }
}

extern "C" void kernel_launch(void* const* d_in, const int* in_sizes, int n_in,
                              void* d_out, int out_size, void* d_ws, size_t ws_size,
                              hipStream_t stream) {
  const float* text = (const float*)d_in[0];   // [64][33][512] f32
  const float* video = (const float*)d_in[1];  // [64][197][512] f32
  const int* mask = (const int*)d_in[2];       // [64][33] i32
  float* out = (float*)d_out;

  char* ws = (char*)d_ws;
  unsigned char* tl8 = (unsigned char*)(ws + TL_OFF);
  unsigned char* ve8 = (unsigned char*)(ws + VE_OFF);
  float* tti = (float*)(ws + TTI_OFF);

  hipLaunchKernelGGL(norm_all_kernel, dim3(BB, 8), dim3(512), 0, stream, text, video, tl8, ve8);
  hipLaunchKernelGGL(sim_kernel, dim3(2048), dim3(512), 0, stream, tl8, ve8, mask, tti);
  hipLaunchKernelGGL(loss_kernel, dim3(1), dim3(1024), 0, stream, tti, out);
}